// Round 8
// baseline (72.609 us; speedup 1.0000x reference)
//
#include <hip/hip_runtime.h>
#include <hip/hip_bf16.h>
#include <math.h>

// NVAR reservoir: out = GELU(poly_feats(x) @ W1 + b1) @ W2 + b2
// B=2 S=512 E=64 DELAY=5 -> L=320, F=51681, tokens=1024
//
// R8: bilinear formulation (R6/R7, verified). New: k_aprep precomputes
// (1) Aimg = byte-exact swizzled A-tile LDS images per 128-token tile
//     (k_main stages via linear coalesced copy -- A-build no longer redone
//      64x per tile), and
// (2) DC = contraction operand in exact C-fragment order (lane-contiguous
//     128B records -> coalesced global reads, kills the conflicted scalar
//     LDS contraction reads; SQ_LDS_BANK_CONFLICT was 2.2M cycles).
// Plus bijective XCD swizzle so each XCD's Mfrag working set ~1.9MB (L2-fit).

#define NF     51681
#define KPAD   352
#define KCHK   11              // 352/32
#define NFR    21              // 336/16
#define NPAD   (NFR * 16)      // 336
#define MT2    128
#define ATS    768             // A-tile row stride BYTES (multiple of 128)

typedef __attribute__((ext_vector_type(8))) short short8;
typedef __attribute__((ext_vector_type(4))) float f32x4;

#define W1C_BYTES  ((size_t)64 * NF * 2)                // 6,615,168
#define MF_BYTES   ((size_t)64 * KPAD * NPAD * 2)       // 15,138,816
#define HBUF_OFF   (W1C_BYTES + MF_BYTES)
#define AIMG_OFF   (HBUF_OFF + (size_t)1024 * 64 * 4)   // hbuf = 256KB
#define AIMG_SH_PER_TILE 49152                          // 128 rows * 384 shorts
#define DC_OFF     (AIMG_OFF + (size_t)8 * AIMG_SH_PER_TILE * 2)
#define DC_SH_PER_TILE 43008                            // 672 recs * 64 lanes

__device__ __forceinline__ unsigned short f2bf(float x) {
    return __bfloat16_as_ushort(__float2bfloat16(x));
}
__device__ __forceinline__ float bf2f(unsigned short h) {
    union { unsigned u; float f; } v; v.u = ((unsigned)h) << 16; return v.f;
}

// ---- k_t: W1c[e][f] = bf16(W1[f][e]) ----
__global__ void k_t(const float* __restrict__ W1, unsigned short* __restrict__ W1c) {
    __shared__ float t[64 * 65];
    const int tid = threadIdx.x;
    const int f0 = blockIdx.x * 64;
    #pragma unroll
    for (int r = 0; r < 16; ++r) {
        int idx = r * 256 + tid;
        int fi = idx >> 6, e = idx & 63;
        t[fi * 65 + e] = (f0 + fi < NF) ? W1[(size_t)(f0 + fi) * 64 + e] : 0.f;
    }
    __syncthreads();
    #pragma unroll
    for (int r = 0; r < 16; ++r) {
        int idx = r * 256 + tid;
        int e = idx >> 6, fi = idx & 63;
        if (f0 + fi < NF)
            W1c[(size_t)e * NF + f0 + fi] = f2bf(t[fi * 65 + e]);
    }
}

// ---- k_pack: Mfrag in MFMA-fragment order (unchanged, verified) ----
__global__ void k_pack(const unsigned short* __restrict__ W1c,
                       unsigned short* __restrict__ Mfrag) {
    const int g = blockIdx.x * 256 + threadIdx.x;       // < 946176 exactly
    const int lane = g & 63;
    const int rec = g >> 6;
    const int nf = rec % NFR;
    const int rec2 = rec / NFR;
    const int kc = rec2 % KCHK;
    const int e = rec2 / KCHK;
    const int i = nf * 16 + (lane & 15);
    const int jb = kc * 32 + ((lane >> 4) << 3);
    const unsigned short* wrow = W1c + (size_t)e * NF;

    __attribute__((aligned(16))) unsigned short v[8];
    #pragma unroll
    for (int r = 0; r < 8; ++r) {
        int j = jb + r;
        unsigned short out = 0;
        if (i < 321 && j < 321) {
            if (j == 320) {
                out = (i == 320) ? wrow[0] : wrow[1 + i];
            } else if (i == 320) {
                out = 0;
            } else {
                int p = min(i, j), q = max(i, j);
                int idx = 321 + p * 320 - ((p * (p - 1)) >> 1) + (q - p);
                unsigned short w = wrow[idx];
                out = (i == j) ? w : f2bf(0.5f * bf2f(w));
            }
        }
        v[r] = out;
    }
    *(short8*)(Mfrag + (size_t)g * 8) = *(short8*)v;
}

// ---- k_aprep: per-tile swizzled A-image + fragment-ordered contraction buf ----
// Aimg[tile][t*384 + s/2 .. +8] = bf16 d'[t][j0..j0+7], j0 = (s ^ ((t&7)<<4))/2
// DC[tile][rec*64+lane], rec = wm*336+mf*84+nf*4+r:
//   value = bf16 d'[wm*64+mf*16+(lane>>4)*4+r][nf*16+(lane&15)]
__global__ void k_aprep(const float* __restrict__ x, unsigned short* __restrict__ Aimg,
                        unsigned short* __restrict__ DC) {
    __shared__ float xwin[132 * 64];
    const int tile = blockIdx.x >> 2;
    const int qtr  = blockIdx.x & 3;
    const int tid = threadIdx.x;
    const int b = tile >> 2, s0 = (tile & 3) * 128;

    for (int idx = tid; idx < 132 * 64; idx += 256) {
        int r = idx >> 6, ee = idx & 63;
        int s = s0 - 4 + r;
        xwin[idx] = (s >= 0) ? x[((b << 9) + s) * 64 + ee] : 0.f;
    }
    __syncthreads();

    // d'(t, j): j<320 -> xwin[(t+j%5)*64 + j/5]; j==320 -> 1; j>320 -> 0
    unsigned short* ai = Aimg + (size_t)tile * AIMG_SH_PER_TILE;
    for (int rec = qtr * 1536 + tid; rec < (qtr + 1) * 1536; rec += 256) {
        int t = rec / 48;
        int s16 = (rec - t * 48) * 16;                  // byte slot in row
        int j0 = (s16 ^ ((t & 7) << 4)) >> 1;
        __attribute__((aligned(16))) unsigned short hv[8];
        #pragma unroll
        for (int r = 0; r < 8; ++r) {
            int j = j0 + r;
            float v;
            if (j < 320) { int e5 = j / 5, k = j - e5 * 5; v = xwin[(t + k) * 64 + e5]; }
            else v = (j == 320) ? 1.0f : 0.f;
            hv[r] = f2bf(v);
        }
        *(short8*)(ai + t * 384 + (s16 >> 1)) = *(short8*)hv;
    }

    unsigned short* dc = DC + (size_t)tile * DC_SH_PER_TILE;
    for (int g = qtr * 10752 + tid; g < (qtr + 1) * 10752; g += 256) {
        int lane = g & 63, rec = g >> 6;
        int r = rec & 3;
        int nf = (rec >> 2) % 21;
        int mfw = rec / 84;                             // wm*4 + mf
        int t = mfw * 16 + ((lane >> 4) << 2) + r;
        int i = nf * 16 + (lane & 15);
        float v;
        if (i < 320) { int e5 = i / 5, k = i - e5 * 5; v = xwin[(t + k) * 64 + e5]; }
        else v = (i == 320) ? 1.0f : 0.f;
        dc[g] = f2bf(v);
    }
}

// ---- k_main: per block (e, tile): C = D' M'_e, h = rowdot(C, D') ----
__global__ __launch_bounds__(1024, 4) void k_main(const unsigned short* __restrict__ Aimg,
                                                  const unsigned short* __restrict__ Mfrag,
                                                  const unsigned short* __restrict__ DC,
                                                  float* __restrict__ hbuf) {
    __shared__ unsigned short At[MT2 * (ATS / 2)];  // 96KB swizzled A image
    __shared__ float hpart[2][8][64];

    const int tid = threadIdx.x;
    const int bid = blockIdx.x;
    // bijective XCD swizzle (512 = 8*64): XCD k gets e in [8k,8k+8), all tiles
    const int wgid = ((bid & 7) << 6) | (bid >> 3);
    const int e = wgid >> 3;
    const int tile = wgid & 7;
    const int tok0 = tile * MT2;

    // stage pre-swizzled A image: linear coalesced copy (m173 pattern)
    {
        const short8* src = (const short8*)(Aimg + (size_t)tile * AIMG_SH_PER_TILE);
        short8* dst = (short8*)At;
        #pragma unroll
        for (int k = 0; k < 6; ++k)
            dst[k * 1024 + tid] = src[k * 1024 + tid];
    }
    __syncthreads();

    const int lane = tid & 63, wv = tid >> 6;   // 16 waves
    const int wm = wv >> 3, wn = wv & 7;        // M-half (64 rows), N-slice (of 8)
    const int nfc = (wn < 5) ? 3 : 2;
    const int nf0 = (wn < 5) ? wn * 3 : 15 + (wn - 5) * 2;
    const unsigned short* Bbase = Mfrag + (size_t)e * (KPAD * NPAD);
    char* Atb = (char*)At;

    f32x4 acc[4][3];
    #pragma unroll
    for (int mf = 0; mf < 4; ++mf)
        #pragma unroll
        for (int q = 0; q < 3; ++q) acc[mf][q] = f32x4{0.f, 0.f, 0.f, 0.f};

    const int arow = wm * 64 + (lane & 15);     // + mf*16
    const int aslot = (lane >> 4) << 4;         // byte sub-offset within 64B k-chunk

    short8 B0[3], B1[3];

#define BLD(DST, KCV)                                                              \
    do { if ((KCV) < KCHK) {                                                       \
        _Pragma("unroll")                                                          \
        for (int q = 0; q < 3; ++q)                                                \
            if (q < nfc)                                                           \
                DST[q] = *(const short8*)(Bbase +                                  \
                    ((size_t)(((KCV) * NFR + nf0 + q) * 64 + lane)) * 8);          \
    } } while (0)

#define STEP(KCV, CUR, NXT)                                                        \
    do {                                                                           \
        short8 Af[4];                                                              \
        _Pragma("unroll")                                                          \
        for (int mf = 0; mf < 4; ++mf) {                                           \
            int t = arow + mf * 16;                                                \
            int jb = (KCV) * 64 + aslot;                                           \
            Af[mf] = *(const short8*)(Atb + t * ATS + (jb ^ ((t & 7) << 4)));      \
        }                                                                          \
        BLD(NXT, (KCV) + 1);                                                       \
        _Pragma("unroll")                                                          \
        for (int mf = 0; mf < 4; ++mf) {                                           \
            _Pragma("unroll")                                                      \
            for (int q = 0; q < 3; ++q)                                            \
                if (q < nfc)                                                       \
                    acc[mf][q] = __builtin_amdgcn_mfma_f32_16x16x32_bf16(          \
                        Af[mf], CUR[q], acc[mf][q], 0, 0, 0);                      \
        }                                                                          \
    } while (0)

    BLD(B0, 0);
    STEP(0, B0, B1);
    STEP(1, B1, B0);
    STEP(2, B0, B1);
    STEP(3, B1, B0);
    STEP(4, B0, B1);
    STEP(5, B1, B0);
    STEP(6, B0, B1);
    STEP(7, B1, B0);
    STEP(8, B0, B1);
    STEP(9, B1, B0);
    STEP(10, B0, B1);
#undef STEP
#undef BLD

    // contraction: s[mf][r] += C * D', D' from fragment-ordered DC (coalesced)
    float s[4][4];
    #pragma unroll
    for (int mf = 0; mf < 4; ++mf)
        #pragma unroll
        for (int r = 0; r < 4; ++r) s[mf][r] = 0.f;

    const unsigned short* DCb = DC + (size_t)tile * DC_SH_PER_TILE + lane;
    #pragma unroll
    for (int q = 0; q < 3; ++q) {
        if (q < nfc) {
            #pragma unroll
            for (int mf = 0; mf < 4; ++mf)
                #pragma unroll
                for (int r = 0; r < 4; ++r) {
                    unsigned short dv =
                        DCb[((wm * 4 + mf) * 84 + (nf0 + q) * 4 + r) * 64];
                    s[mf][r] += acc[mf][q][r] * bf2f(dv);
                }
        }
    }
    // reduce across the 16 lanes of each i-column group
    #pragma unroll
    for (int mf = 0; mf < 4; ++mf)
        #pragma unroll
        for (int r = 0; r < 4; ++r) {
            float v = s[mf][r];
            v += __shfl_xor(v, 1);
            v += __shfl_xor(v, 2);
            v += __shfl_xor(v, 4);
            v += __shfl_xor(v, 8);
            s[mf][r] = v;
        }
    if ((lane & 15) == 0) {
        #pragma unroll
        for (int mf = 0; mf < 4; ++mf)
            #pragma unroll
            for (int r = 0; r < 4; ++r)
                hpart[wm][wn][mf * 16 + ((lane >> 4) << 2) + r] = s[mf][r];
    }
    __syncthreads();
    if (tid < 128) {
        int wmx = tid >> 6, tl = tid & 63;
        float v = 0.f;
        #pragma unroll
        for (int w = 0; w < 8; ++w) v += hpart[wmx][w][tl];
        hbuf[(size_t)(tok0 + wmx * 64 + tl) * 64 + e] = v;
    }
}

// ---- epilogue: out = GELU(hbuf + b1) @ W2 + b2 ----
__global__ void k_epi(const float* __restrict__ hbuf, const float* __restrict__ b1,
                      const float* __restrict__ W2, const float* __restrict__ b2,
                      float* __restrict__ out) {
    __shared__ float h[4 * 64];
    int tid = threadIdx.x;
    int t = tid >> 6, e = tid & 63;
    int token = blockIdx.x * 4 + t;
    float pre = hbuf[token * 64 + e] + b1[e];
    float hv = 0.5f * pre * (1.0f + erff(pre * 0.70710678118654752f));  // exact GELU
    h[t * 64 + e] = hv;
    __syncthreads();
    float s = b2[e];
    #pragma unroll 8
    for (int ee = 0; ee < 64; ++ee)
        s += h[t * 64 + ee] * W2[ee * 64 + e];
    out[token * 64 + e] = s;
}

extern "C" void kernel_launch(void* const* d_in, const int* in_sizes, int n_in,
                              void* d_out, int out_size, void* d_ws, size_t ws_size,
                              hipStream_t stream) {
    const float* x  = (const float*)d_in[0];
    const float* W1 = (const float*)d_in[1];
    const float* b1 = (const float*)d_in[2];
    const float* W2 = (const float*)d_in[3];
    const float* b2 = (const float*)d_in[4];
    float* out = (float*)d_out;

    unsigned short* W1c   = (unsigned short*)d_ws;
    unsigned short* Mfrag = (unsigned short*)((char*)d_ws + W1C_BYTES);
    float* hbuf           = (float*)((char*)d_ws + HBUF_OFF);
    unsigned short* Aimg  = (unsigned short*)((char*)d_ws + AIMG_OFF);
    unsigned short* DC    = (unsigned short*)((char*)d_ws + DC_OFF);

    k_t<<<(NF + 63) / 64, 256, 0, stream>>>(W1, W1c);
    k_pack<<<3696, 256, 0, stream>>>(W1c, Mfrag);
    k_aprep<<<32, 256, 0, stream>>>(x, Aimg, DC);
    k_main<<<512, 1024, 0, stream>>>(Aimg, Mfrag, DC, hbuf);
    k_epi<<<256, 256, 0, stream>>>(hbuf, b1, W2, b2, out);
}